// Round 6
// baseline (98.802 us; speedup 1.0000x reference)
//
#include <hip/hip_runtime.h>

typedef __attribute__((ext_vector_type(8))) _Float16 half8;
typedef __attribute__((ext_vector_type(4))) float f32x4;

#define N_ROWS 32768
#define D 128
#define K_EMB 1024
#define BIAS 512.0f   // keeps score = ||e||^2 - 2x.e + BIAS > 0 (||x||^2 << 512 whp)

// ws: Ef fp16 fragment-linear (256 KB) + enb (4 KB)
#define WS_EF 0
#define WS_ENB (K_EMB * D * 2)

// ---- prep: emb -> fragment-linear fp16 + (||e||^2 + BIAS) ; zero loss ----
// half8 index: ct*256 + kc*64 + lane  (lane = quad*16 + l15)
// holds E[col = ct*16+l15][dims kc*32 + quad*8 .. +8]  (MFMA B-operand layout)
__global__ __launch_bounds__(256) void vq_prep(const float* __restrict__ emb,
                                               half8* __restrict__ Ef,
                                               float* __restrict__ enb,
                                               float* __restrict__ loss_slot) {
    int t = blockIdx.x * 256 + threadIdx.x;   // 16384: 1024 cols x 16 parts
    int col = t >> 4, part = t & 15;          // dims part*8 .. part*8+8
    int kc = part >> 2, quad = part & 3;
    int ct = col >> 4, l15 = col & 15;

    const float4* e4 = (const float4*)(emb + (size_t)col * D + part * 8);
    float4 a = e4[0], b = e4[1];
    float xv[8] = {a.x, a.y, a.z, a.w, b.x, b.y, b.z, b.w};
    half8 sh;
    float s = 0.0f;
    #pragma unroll
    for (int j = 0; j < 8; ++j) {
        float f = xv[j];
        s += f * f;
        sh[j] = (_Float16)f;
    }
    Ef[ct * 256 + kc * 64 + quad * 16 + l15] = sh;
    #pragma unroll
    for (int off = 8; off; off >>= 1) s += __shfl_down(s, off, 16);
    if (part == 0) enb[col] = s + BIAS;
    if (t == 0) *loss_slot = 0.0f;
}

// ---- main: streaming fp16 MFMA + packed-key top-2/wave + exact recheck-8 ----
// grid 512 (2 blocks/CU), block 256 = 4 waves; block owns 64 rows (rt=4/wave);
// wave w sweeps col-tiles w*16 .. w*16+15 (256 cols). B streamed global->VGPR.
__global__ __launch_bounds__(256, 2) void vq_main(const float* __restrict__ x,
                                                  const half8* __restrict__ Ef,
                                                  const float* __restrict__ enb,
                                                  const float* __restrict__ emb,
                                                  float* __restrict__ outq,
                                                  float* __restrict__ loss_slot) {
    __shared__ float Xs[64 * 132];   // fp32 x rows, stride 132 (conflict-free)
    __shared__ uint2 sTop[4][64];
    __shared__ float lsum[4];

    const int t = threadIdx.x;
    const int w = t >> 6;
    const int lane = t & 63;
    const int l15 = lane & 15;
    const int quad = lane >> 4;
    const size_t rbase = (size_t)blockIdx.x * 64;

    // stage x tile (64 rows x 128 fp32) into LDS, coalesced
    {
        const float4* xg = (const float4*)(x + rbase * D);
        #pragma unroll
        for (int i = 0; i < 8; ++i) {
            int f = t + i * 256;             // 0..2047 float4s
            int r = f >> 5, c4 = f & 31;
            *(float4*)&Xs[r * 132 + c4 * 4] = xg[f];
        }
    }

    // hoist enb for this wave's 16 col-tiles (col = (w*16+i)*16 + l15)
    float enk[16];
    #pragma unroll
    for (int i = 0; i < 16; ++i) enk[i] = enb[(w * 16 + i) * 16 + l15];

    __syncthreads();

    // A fragments (fp16): 4 row-tiles x 4 k-chunks = 64 VGPRs
    half8 afr[4][4];
    #pragma unroll
    for (int rt = 0; rt < 4; ++rt)
        #pragma unroll
        for (int kc = 0; kc < 4; ++kc) {
            const float* sp = &Xs[(rt * 16 + l15) * 132 + kc * 32 + quad * 8];
            float4 a = *(const float4*)sp;
            float4 b = *(const float4*)(sp + 4);
            half8 sh;
            sh[0] = (_Float16)a.x; sh[1] = (_Float16)a.y;
            sh[2] = (_Float16)a.z; sh[3] = (_Float16)a.w;
            sh[4] = (_Float16)b.x; sh[5] = (_Float16)b.y;
            sh[6] = (_Float16)b.z; sh[7] = (_Float16)b.w;
            afr[rt][kc] = sh;
        }

    // packed-key top-2: positive fp32 score with col in low 10 mantissa bits
    float k1[16], k2[16];
    #pragma unroll
    for (int s = 0; s < 16; ++s) { k1[s] = 3.0e38f; k2[s] = 3.0e38f; }

    // B register double-buffer (global -> VGPR, 1KB coalesced per load, L2-hot)
    const half8* bp = Ef + (size_t)(w * 16) * 256 + lane;
    half8 b0 = bp[0], b1 = bp[64], b2 = bp[128], b3 = bp[192];

    #pragma unroll 2
    for (int i = 0; i < 16; ++i) {
        const int ct = w * 16 + i;
        const int colbase = ct * 16 + l15;
        half8 n0, n1, n2, n3;
        if (i < 15) {
            const half8* np = Ef + (size_t)(ct + 1) * 256 + lane;
            n0 = np[0]; n1 = np[64]; n2 = np[128]; n3 = np[192];
        }
        f32x4 acc[4] = {{0.f,0.f,0.f,0.f},{0.f,0.f,0.f,0.f},
                        {0.f,0.f,0.f,0.f},{0.f,0.f,0.f,0.f}};
        #pragma unroll
        for (int rt = 0; rt < 4; ++rt)
            acc[rt] = __builtin_amdgcn_mfma_f32_16x16x32_f16(afr[rt][0], b0, acc[rt], 0, 0, 0);
        #pragma unroll
        for (int rt = 0; rt < 4; ++rt)
            acc[rt] = __builtin_amdgcn_mfma_f32_16x16x32_f16(afr[rt][1], b1, acc[rt], 0, 0, 0);
        #pragma unroll
        for (int rt = 0; rt < 4; ++rt)
            acc[rt] = __builtin_amdgcn_mfma_f32_16x16x32_f16(afr[rt][2], b2, acc[rt], 0, 0, 0);
        #pragma unroll
        for (int rt = 0; rt < 4; ++rt)
            acc[rt] = __builtin_amdgcn_mfma_f32_16x16x32_f16(afr[rt][3], b3, acc[rt], 0, 0, 0);

        #pragma unroll
        for (int rt = 0; rt < 4; ++rt)
            #pragma unroll
            for (int r = 0; r < 4; ++r) {
                float s = fmaf(acc[rt][r], -2.0f, enk[i]);          // > 0 by BIAS
                unsigned key = (__float_as_uint(s) & 0xFFFFFC00u) | (unsigned)colbase;
                float kf = __uint_as_float(key);                    // monotone, tie->low col
                int sl = rt * 4 + r;
                k2[sl] = __builtin_amdgcn_fmed3f(k1[sl], k2[sl], kf);
                k1[sl] = fminf(k1[sl], kf);
            }
        b0 = n0; b1 = n1; b2 = n2; b3 = n3;
    }

    // merge sorted pairs across the 16 lanes of each quad-row; publish per wave
    #pragma unroll
    for (int s = 0; s < 16; ++s) {
        float a1 = k1[s], a2 = k2[s];
        #pragma unroll
        for (int m = 1; m < 16; m <<= 1) {
            float o1 = __shfl_xor(a1, m, 16);
            float o2 = __shfl_xor(a2, m, 16);
            float mx = fmaxf(a1, o1);
            a1 = fminf(a1, o1);
            a2 = fminf(mx, fminf(a2, o2));
        }
        if (l15 == 0) {
            int rib = (s >> 2) * 16 + quad * 4 + (s & 3);
            sTop[w][rib] = make_uint2(__float_as_uint(a1), __float_as_uint(a2));
        }
    }
    __syncthreads();

    // fused epilogue: EXACT fp32 recheck of all 8 wave-candidates, gather, loss
    float lacc = 0.0f;
    #pragma unroll
    for (int rep = 0; rep < 2; ++rep) {
        int rib = rep * 32 + (t >> 3);       // 32 rows/pass, 8 lanes/row
        int l8 = t & 7;
        size_t row = rbase + rib;

        int cols[8];
        #pragma unroll
        for (int j = 0; j < 4; ++j) {
            uint2 tp = sTop[j][rib];
            cols[j * 2]     = (int)(tp.x & 1023u);
            cols[j * 2 + 1] = (int)(tp.y & 1023u);
        }

        float4 xs[4];
        #pragma unroll
        for (int j = 0; j < 4; ++j) xs[j] = *(const float4*)&Xs[rib * 132 + l8 * 16 + j * 4];

        float bd = 3.0e38f;
        int bc = 0x7fffffff;
        #pragma unroll
        for (int c = 0; c < 8; ++c) {
            const float4* ep = (const float4*)(emb + (size_t)cols[c] * D + l8 * 16);
            float d = 0.f;
            #pragma unroll
            for (int j = 0; j < 4; ++j) {
                float4 e = ep[j];
                float dx = e.x - xs[j].x, dy = e.y - xs[j].y,
                      dz = e.z - xs[j].z, dw = e.w - xs[j].w;
                d += dx * dx + dy * dy + dz * dz + dw * dw;
            }
            #pragma unroll
            for (int off = 4; off; off >>= 1) d += __shfl_xor(d, off, 8);
            if (d < bd || (d == bd && cols[c] < bc)) { bd = d; bc = cols[c]; }  // np tie-break
        }

        // reload winner (L1-hot) and write q
        const float4* bp2 = (const float4*)(emb + (size_t)bc * D + l8 * 16);
        float4* dst = (float4*)(outq + row * D + l8 * 16);
        #pragma unroll
        for (int j = 0; j < 4; ++j) dst[j] = bp2[j];
        if (l8 == 0) lacc += bd;
    }
    #pragma unroll
    for (int off = 32; off; off >>= 1) lacc += __shfl_down(lacc, off, 64);
    if (lane == 0) lsum[w] = lacc;
    __syncthreads();
    if (t == 0) atomicAdd(loss_slot, 1.5f * ((lsum[0] + lsum[1]) + (lsum[2] + lsum[3])));
}

extern "C" void kernel_launch(void* const* d_in, const int* in_sizes, int n_in,
                              void* d_out, int out_size, void* d_ws, size_t ws_size,
                              hipStream_t stream) {
    const float* x   = (const float*)d_in[0];   // [32768,128]
    const float* emb = (const float*)d_in[1];   // [1024,128]
    float* outq      = (float*)d_out;
    float* loss_slot = outq + (size_t)N_ROWS * D;

    char* ws = (char*)d_ws;
    half8* Ef  = (half8*)(ws + WS_EF);
    float* enb = (float*)(ws + WS_ENB);

    vq_prep<<<64, 256, 0, stream>>>(emb, Ef, enb, loss_slot);
    vq_main<<<512, 256, 0, stream>>>(x, Ef, enb, emb, outq, loss_slot);
}